// Round 3
// baseline (353.495 us; speedup 1.0000x reference)
//
#include <hip/hip_runtime.h>
#include <hip/hip_bf16.h>

#define IN_DIM  128
#define HID_DIM 128
#define OUT_DIM 64

typedef unsigned short ushort_t;
struct ushort4_t { ushort_t x, y, z, w; };
typedef __attribute__((ext_vector_type(8))) short bf16x8;   // 8 bf16 (4 VGPRs)
typedef __attribute__((ext_vector_type(4))) float f32x4;    // MFMA acc

__device__ __forceinline__ float bf2f(ushort_t u) {
    return __uint_as_float(((unsigned int)u) << 16);
}
__device__ __forceinline__ short f2bf_s(float v) {
    __hip_bfloat16 t = __float2bfloat16(v);
    return *(short*)&t;
}
__device__ __forceinline__ unsigned int pack2(float a, float b) {
    return ((unsigned int)(ushort_t)f2bf_s(b) << 16) | (ushort_t)f2bf_s(a);
}

// ---------------- FUSED: gemm1 (odd blocks) || count+rank (even blocks) ----------------
// count role is device-atomic-throughput-bound (~23G/s, ~67us) and hides the whole GEMM.
__global__ __launch_bounds__(256, 2) void fused_gemm1_count(
        const float* __restrict__ x, const float* __restrict__ W,
        unsigned int* __restrict__ h,
        const int* __restrict__ dst, int* __restrict__ cnt, int* __restrict__ rank,
        int N, int E, int NT) {
    const int bid = blockIdx.x;
    const int tid = threadIdx.x;

    if (bid & 1) {
        // ---- GEMM1 role ----
        const int lane = tid & 63;
        const int m    = lane & 15;
        const int quad = lane >> 4;
        const int gw   = (bid >> 1) * 4 + (tid >> 6);
        const int NW   = 1024;                  // 256 blocks x 4 waves

        bf16x8 a[8][4];                         // 8 col-tiles x 4 k-chunks
        #pragma unroll
        for (int ct = 0; ct < 8; ++ct)
            #pragma unroll
            for (int kc = 0; kc < 4; ++kc)
                #pragma unroll
                for (int j = 0; j < 8; ++j)
                    a[ct][kc][j] = f2bf_s(W[(size_t)(kc * 32 + quad * 8 + j) * HID_DIM + ct * 16 + m]);

        for (int t = gw; t < NT; t += NW) {
            const int n0 = t * 16;
            int node = n0 + m; if (node >= N) node = N - 1;
            const float* xr = x + (size_t)node * IN_DIM + quad * 8;
            f32x4 acc[8];
            #pragma unroll
            for (int ct = 0; ct < 8; ++ct) acc[ct] = (f32x4){0.f, 0.f, 0.f, 0.f};
            #pragma unroll
            for (int kc = 0; kc < 4; ++kc) {
                const float4 v0 = *(const float4*)(xr + kc * 32);
                const float4 v1 = *(const float4*)(xr + kc * 32 + 4);
                bf16x8 b;
                b[0] = f2bf_s(v0.x); b[1] = f2bf_s(v0.y); b[2] = f2bf_s(v0.z); b[3] = f2bf_s(v0.w);
                b[4] = f2bf_s(v1.x); b[5] = f2bf_s(v1.y); b[6] = f2bf_s(v1.z); b[7] = f2bf_s(v1.w);
                #pragma unroll
                for (int ct = 0; ct < 8; ++ct)
                    acc[ct] = __builtin_amdgcn_mfma_f32_16x16x32_bf16(a[ct][kc], b, acc[ct], 0, 0, 0);
            }
            if (n0 + m < N) {
                unsigned int* o = h + (size_t)(n0 + m) * (HID_DIM / 2) + quad * 2;
                #pragma unroll
                for (int ct = 0; ct < 8; ++ct) {
                    uint2 pv;
                    pv.x = pack2(acc[ct][0], acc[ct][1]);
                    pv.y = pack2(acc[ct][2], acc[ct][3]);
                    *(uint2*)(o + ct * 8) = pv;
                }
            }
        }
    } else {
        // ---- count + rank role ----
        const int ct = (bid >> 1) * 256 + tid;
        const int CT = 256 * 256;
        const int nq = E >> 2;
        const int4* d4 = (const int4*)dst;
        for (int q = ct; q < nq; q += CT) {
            const int4 d = d4[q];
            int4 r;
            r.x = atomicAdd(&cnt[d.x], 1);
            r.y = atomicAdd(&cnt[d.y], 1);
            r.z = atomicAdd(&cnt[d.z], 1);
            r.w = atomicAdd(&cnt[d.w], 1);
            ((int4*)rank)[q] = r;
        }
        for (int e = (nq << 2) + ct; e < E; e += CT)
            rank[e] = atomicAdd(&cnt[dst[e]], 1);
    }
}

// ---------------- scan: per-block sums of PADDED counts ((cnt+3)&~3), dinv folded in ----------------
__global__ void scan_partial(const int* __restrict__ cnt, int* __restrict__ bsum,
                             float* __restrict__ dinv, int N) {
    __shared__ int wsum[4];
    const int t = threadIdx.x;
    const int base = blockIdx.x * 2048 + t * 8;
    int s = 0;
    #pragma unroll
    for (int i = 0; i < 8; ++i) {
        if (base + i < N) {
            const int c = cnt[base + i];
            dinv[base + i] = rsqrtf((float)(c + 1));   // +1 self loop
            s += (c + 3) & ~3;
        }
    }
    #pragma unroll
    for (int off = 32; off > 0; off >>= 1) s += __shfl_down(s, off);
    const int lane = t & 63, w = t >> 6;
    if (lane == 0) wsum[w] = s;
    __syncthreads();
    if (t == 0) bsum[blockIdx.x] = wsum[0] + wsum[1] + wsum[2] + wsum[3];
}

// scan_write: computes row_start (record units, multiples of 4) and writes -1 to pad slots.
// Block offset computed in-kernel from raw bsum (S is tiny), no separate scan launch.
__global__ void scan_write(const int* __restrict__ cnt, const int* __restrict__ bsum,
                           int* __restrict__ row_start, int* __restrict__ pack, int N) {
    __shared__ int wsum[4];
    __shared__ int blockoff;
    const int t = threadIdx.x;
    if (t < 64) {
        int a = 0;
        for (int idx = t; idx < blockIdx.x; idx += 64) a += bsum[idx];
        #pragma unroll
        for (int off = 32; off > 0; off >>= 1) a += __shfl_down(a, off);
        if (t == 0) blockoff = a;
    }
    const int base = blockIdx.x * 2048 + t * 8;
    int c[8], v[8];
    #pragma unroll
    for (int i = 0; i < 8; ++i) {
        c[i] = (base + i < N) ? cnt[base + i] : 0;
        v[i] = (c[i] + 3) & ~3;
    }
    int s = v[0] + v[1] + v[2] + v[3] + v[4] + v[5] + v[6] + v[7];
    const int lane = t & 63, w = t >> 6;
    int incl = s;
    #pragma unroll
    for (int off = 1; off < 64; off <<= 1) {
        int u = __shfl_up(incl, off);
        if (lane >= off) incl += u;
    }
    if (lane == 63) wsum[w] = incl;
    __syncthreads();
    int woff = 0;
    for (int i = 0; i < w; ++i) woff += wsum[i];
    int run = blockoff + woff + (incl - s);
    #pragma unroll
    for (int i = 0; i < 8; ++i) {
        if (base + i < N) {
            row_start[base + i] = run;
            for (int p = c[i]; p < v[i]; ++p) pack[run + p] = -1;   // pad slots
            run += v[i];
        }
    }
}

// ---------------- fill packed CSR records {src} (4B), no atomics, int4-vectorized ----------------
__global__ void fill_pack4(const int* __restrict__ src, const int* __restrict__ dst,
                           const int* __restrict__ rank, const int* __restrict__ row_start,
                           int E, int* __restrict__ pack) {
    const int q = blockIdx.x * blockDim.x + threadIdx.x;
    const int nq = E >> 2;
    if (q < nq) {
        const int4 s = ((const int4*)src)[q];
        const int4 d = ((const int4*)dst)[q];
        const int4 r = ((const int4*)rank)[q];
        pack[row_start[d.x] + r.x] = s.x;
        pack[row_start[d.y] + r.y] = s.y;
        pack[row_start[d.z] + r.z] = s.z;
        pack[row_start[d.w] + r.w] = s.w;
    }
    if (q == 0) {   // tail (E not multiple of 4)
        for (int e = nq << 2; e < E; ++e)
            pack[row_start[dst[e]] + rank[e]] = src[e];
    }
}

// ---------------- GEMM2 (MFMA): h2[N,64](bf16) = agg_relu[N,128](bf16) @ W2[128,64] ----------------
// agg already has bias+relu applied -> b-frag is a raw 16B load.
__global__ __launch_bounds__(256) void gemm2_mfma(
        const ushort_t* __restrict__ agg,
        const float* __restrict__ W2, unsigned int* __restrict__ h2,
        int N, int NT, int NW) {
    const int tid  = threadIdx.x;
    const int lane = tid & 63;
    const int m    = lane & 15;
    const int quad = lane >> 4;
    const int gw   = blockIdx.x * 4 + (tid >> 6);

    bf16x8 a[4][4];                         // 4 col-tiles x 4 k-chunks
    #pragma unroll
    for (int ct = 0; ct < 4; ++ct)
        #pragma unroll
        for (int kc = 0; kc < 4; ++kc)
            #pragma unroll
            for (int j = 0; j < 8; ++j)
                a[ct][kc][j] = f2bf_s(W2[(size_t)(kc * 32 + quad * 8 + j) * OUT_DIM + ct * 16 + m]);

    for (int t = gw; t < NT; t += NW) {
        const int n0 = t * 16;
        int node = n0 + m; if (node >= N) node = N - 1;
        const ushort_t* ar = agg + (size_t)node * HID_DIM + quad * 8;
        f32x4 acc[4];
        #pragma unroll
        for (int ct = 0; ct < 4; ++ct) acc[ct] = (f32x4){0.f, 0.f, 0.f, 0.f};
        #pragma unroll
        for (int kc = 0; kc < 4; ++kc) {
            const bf16x8 b = *(const bf16x8*)(ar + kc * 32);
            #pragma unroll
            for (int ct = 0; ct < 4; ++ct)
                acc[ct] = __builtin_amdgcn_mfma_f32_16x16x32_bf16(a[ct][kc], b, acc[ct], 0, 0, 0);
        }
        if (n0 + m < N) {
            unsigned int* o = h2 + (size_t)(n0 + m) * (OUT_DIM / 2) + quad * 2;
            #pragma unroll
            for (int ct = 0; ct < 4; ++ct) {
                uint2 pv;
                pv.x = pack2(acc[ct][0], acc[ct][1]);
                pv.y = pack2(acc[ct][2], acc[ct][3]);
                *(uint2*)(o + ct * 8) = pv;
            }
        }
    }
}

// ---------------- gather aggregation over 4B {src} records; norm on the fly ----------------
// pad records are src=-1 -> norm forced to 0. bias added pre-loop (commutes), relu post-loop.
template<int D, bool BF16_OUT, bool RELU>
__global__ void gather_bf16(const ushort_t* __restrict__ h, const int* __restrict__ pack,
                            const int* __restrict__ row_start, const int* __restrict__ cnt,
                            const float* __restrict__ dinv, const float* __restrict__ bias,
                            int N, void* __restrict__ outv) {
    const int TPN = D / 4;
    const int NPB = 256 / TPN;
    const int t = threadIdx.x;
    const int node = blockIdx.x * NPB + t / TPN;
    if (node >= N) return;
    const int f = (t & (TPN - 1)) * 4;
    const float dd = dinv[node];

    const ushort4_t self = *(const ushort4_t*)(h + (size_t)node * D + f);
    const float sn = dd * dd;
    float4 acc;
    acc.x = bf2f(self.x) * sn; acc.y = bf2f(self.y) * sn;
    acc.z = bf2f(self.z) * sn; acc.w = bf2f(self.w) * sn;
    const float4 bv = *(const float4*)(bias + f);
    acc.x += bv.x; acc.y += bv.y; acc.z += bv.z; acc.w += bv.w;

    const int* pk = pack + row_start[node];        // 16B-aligned (start % 4 == 0)
    const int cpad = (cnt[node] + 3) & ~3;
    for (int e = 0; e < cpad; e += 4) {
        const int4 s4 = *(const int4*)(pk + e);
        const int i0 = s4.x < 0 ? 0 : s4.x;
        const int i1 = s4.y < 0 ? 0 : s4.y;
        const int i2 = s4.z < 0 ? 0 : s4.z;
        const int i3 = s4.w < 0 ? 0 : s4.w;
        const float n0 = s4.x < 0 ? 0.f : dinv[i0] * dd;
        const float n1 = s4.y < 0 ? 0.f : dinv[i1] * dd;
        const float n2 = s4.z < 0 ? 0.f : dinv[i2] * dd;
        const float n3 = s4.w < 0 ? 0.f : dinv[i3] * dd;
        const ushort4_t v0 = *(const ushort4_t*)(h + (size_t)i0 * D + f);
        const ushort4_t v1 = *(const ushort4_t*)(h + (size_t)i1 * D + f);
        const ushort4_t v2 = *(const ushort4_t*)(h + (size_t)i2 * D + f);
        const ushort4_t v3 = *(const ushort4_t*)(h + (size_t)i3 * D + f);
        acc.x += bf2f(v0.x) * n0; acc.y += bf2f(v0.y) * n0;
        acc.z += bf2f(v0.z) * n0; acc.w += bf2f(v0.w) * n0;
        acc.x += bf2f(v1.x) * n1; acc.y += bf2f(v1.y) * n1;
        acc.z += bf2f(v1.z) * n1; acc.w += bf2f(v1.w) * n1;
        acc.x += bf2f(v2.x) * n2; acc.y += bf2f(v2.y) * n2;
        acc.z += bf2f(v2.z) * n2; acc.w += bf2f(v2.w) * n2;
        acc.x += bf2f(v3.x) * n3; acc.y += bf2f(v3.y) * n3;
        acc.z += bf2f(v3.z) * n3; acc.w += bf2f(v3.w) * n3;
    }
    if (RELU) {
        acc.x = fmaxf(acc.x, 0.f); acc.y = fmaxf(acc.y, 0.f);
        acc.z = fmaxf(acc.z, 0.f); acc.w = fmaxf(acc.w, 0.f);
    }
    if (BF16_OUT) {
        unsigned int* out = (unsigned int*)outv;
        uint2 pv;
        pv.x = pack2(acc.x, acc.y);
        pv.y = pack2(acc.z, acc.w);
        *(uint2*)(out + ((size_t)node * D + f) / 2) = pv;
    } else {
        float* out = (float*)outv;
        *(float4*)(out + (size_t)node * D + f) = acc;
    }
}

extern "C" void kernel_launch(void* const* d_in, const int* in_sizes, int n_in,
                              void* d_out, int out_size, void* d_ws, size_t ws_size,
                              hipStream_t stream) {
    const float* x   = (const float*)d_in[0];
    const int*   ei  = (const int*)  d_in[1];
    const float* W1  = (const float*)d_in[2];
    const float* b1  = (const float*)d_in[3];
    const float* W2  = (const float*)d_in[4];
    const float* b2  = (const float*)d_in[5];
    float* out = (float*)d_out;

    const int N = in_sizes[0] / IN_DIM;     // 100000
    const int E = in_sizes[1] / 2;          // 1600000
    const int* src = ei;                    // edge_index[0]
    const int* dst = ei + E;                // edge_index[1]

    // workspace layout (4B units):
    // dinv[N] | cnt[N] | row_start[N] | bsum[1024] | align | pack[E+4N] int
    // | h1[N*64] u32 (bf16 h1, reused as h2) | agg1[N*64] u32 (bf16; rank aliases it)
    const int PACK_CAP = E + 4 * N;
    float* dinv      = (float*)d_ws;
    int*   cnt       = (int*)(dinv + N);
    int*   row_start = cnt + N;
    int*   bsum      = row_start + N;
    size_t off       = (size_t)(3 * N + 1024);
    off = (off + 3) & ~(size_t)3;           // 16B-align pack
    int*   pack      = (int*)d_ws + off;
    unsigned int* h1 = (unsigned int*)(pack + PACK_CAP);
    unsigned int* agg1 = h1 + (size_t)N * (HID_DIM / 2);
    int*   rank      = (int*)agg1;          // alive only until fill_pack (E <= N*64)
    unsigned int* h2 = h1;                  // reuse after gather128

    const int B = 256;
    const int S = (N + 2047) / 2048;        // scan blocks
    const int NT = (N + 15) / 16;           // 16-node MFMA tiles

    // 1) CSR counts + rank, fused with GEMM1 (independent work hides atomic throughput floor)
    hipMemsetAsync(cnt, 0, (size_t)N * sizeof(int), stream);
    fused_gemm1_count<<<512, 256, 0, stream>>>(x, W1, h1, dst, cnt, rank, N, E, NT);

    // 2) scan (dinv folded into scan_partial; scan_write self-computes block offsets + pads)
    scan_partial<<<S, 256, 0, stream>>>(cnt, bsum, dinv, N);
    scan_write<<<S, 256, 0, stream>>>(cnt, bsum, row_start, pack, N);

    // 3) fill packed CSR records (4B src-only)
    fill_pack4<<<((E >> 2) + B - 1) / B, B, 0, stream>>>(src, dst, rank, row_start, E, pack);

    // 4) agg1 = relu(gather(h1) + b1)  (bf16 out; overwrites rank)
    gather_bf16<HID_DIM, true, true><<<(N + 7) / 8, 256, 0, stream>>>(
        (const ushort_t*)h1, pack, row_start, cnt, dinv, b1, N, (void*)agg1);

    // 5) h2 = agg1 @ W2  (bf16 out, MFMA, raw b-frag loads)
    gemm2_mfma<<<768, 256, 0, stream>>>(
        (const ushort_t*)agg1, W2, h2, N, NT, 768 * 4);

    // 6) out = b2 + gather(h2)  (f32 out)
    gather_bf16<OUT_DIM, false, false><<<(N + 15) / 16, 256, 0, stream>>>(
        (const ushort_t*)h2, pack, row_start, cnt, dinv, b2, N, (void*)out);
}

// Round 4
// 312.247 us; speedup vs baseline: 1.1321x; 1.1321x over previous
//
#include <hip/hip_runtime.h>
#include <hip/hip_bf16.h>

#define IN_DIM  128
#define HID_DIM 128
#define OUT_DIM 64

typedef unsigned short ushort_t;
struct ushort4_t { ushort_t x, y, z, w; };
typedef __attribute__((ext_vector_type(8))) short bf16x8;   // 8 bf16 (4 VGPRs)
typedef __attribute__((ext_vector_type(4))) float f32x4;    // MFMA acc

__device__ __forceinline__ float bf2f(ushort_t u) {
    return __uint_as_float(((unsigned int)u) << 16);
}
__device__ __forceinline__ short f2bf_s(float v) {
    __hip_bfloat16 t = __float2bfloat16(v);
    return *(short*)&t;
}
__device__ __forceinline__ unsigned int pack2(float a, float b) {
    return ((unsigned int)(ushort_t)f2bf_s(b) << 16) | (ushort_t)f2bf_s(a);
}

// ---------------- FUSED: gemm1 (odd blocks) || count+rank (even blocks) ----------------
// count role is device-atomic-throughput-bound (~24G atomics/s, ~67us) and hides the GEMM.
__global__ __launch_bounds__(256, 2) void fused_gemm1_count(
        const float* __restrict__ x, const float* __restrict__ W,
        unsigned int* __restrict__ h,
        const int* __restrict__ dst, int* __restrict__ cnt, int* __restrict__ rank,
        int N, int E, int NT) {
    const int bid = blockIdx.x;
    const int tid = threadIdx.x;

    if (bid & 1) {
        // ---- GEMM1 role ----
        const int lane = tid & 63;
        const int m    = lane & 15;
        const int quad = lane >> 4;
        const int gw   = (bid >> 1) * 4 + (tid >> 6);
        const int NW   = 1024;                  // 256 blocks x 4 waves

        bf16x8 a[8][4];                         // 8 col-tiles x 4 k-chunks
        #pragma unroll
        for (int ct = 0; ct < 8; ++ct)
            #pragma unroll
            for (int kc = 0; kc < 4; ++kc)
                #pragma unroll
                for (int j = 0; j < 8; ++j)
                    a[ct][kc][j] = f2bf_s(W[(size_t)(kc * 32 + quad * 8 + j) * HID_DIM + ct * 16 + m]);

        for (int t = gw; t < NT; t += NW) {
            const int n0 = t * 16;
            int node = n0 + m; if (node >= N) node = N - 1;
            const float* xr = x + (size_t)node * IN_DIM + quad * 8;
            f32x4 acc[8];
            #pragma unroll
            for (int ct = 0; ct < 8; ++ct) acc[ct] = (f32x4){0.f, 0.f, 0.f, 0.f};
            #pragma unroll
            for (int kc = 0; kc < 4; ++kc) {
                const float4 v0 = *(const float4*)(xr + kc * 32);
                const float4 v1 = *(const float4*)(xr + kc * 32 + 4);
                bf16x8 b;
                b[0] = f2bf_s(v0.x); b[1] = f2bf_s(v0.y); b[2] = f2bf_s(v0.z); b[3] = f2bf_s(v0.w);
                b[4] = f2bf_s(v1.x); b[5] = f2bf_s(v1.y); b[6] = f2bf_s(v1.z); b[7] = f2bf_s(v1.w);
                #pragma unroll
                for (int ct = 0; ct < 8; ++ct)
                    acc[ct] = __builtin_amdgcn_mfma_f32_16x16x32_bf16(a[ct][kc], b, acc[ct], 0, 0, 0);
            }
            if (n0 + m < N) {
                unsigned int* o = h + (size_t)(n0 + m) * (HID_DIM / 2) + quad * 2;
                #pragma unroll
                for (int ct = 0; ct < 8; ++ct) {
                    uint2 pv;
                    pv.x = pack2(acc[ct][0], acc[ct][1]);
                    pv.y = pack2(acc[ct][2], acc[ct][3]);
                    *(uint2*)(o + ct * 8) = pv;
                }
            }
        }
    } else {
        // ---- count + rank role ----
        const int ct = (bid >> 1) * 256 + tid;
        const int CT = 256 * 256;
        const int nq = E >> 2;
        const int4* d4 = (const int4*)dst;
        for (int q = ct; q < nq; q += CT) {
            const int4 d = d4[q];
            int4 r;
            r.x = atomicAdd(&cnt[d.x], 1);
            r.y = atomicAdd(&cnt[d.y], 1);
            r.z = atomicAdd(&cnt[d.z], 1);
            r.w = atomicAdd(&cnt[d.w], 1);
            ((int4*)rank)[q] = r;
        }
        for (int e = (nq << 2) + ct; e < E; e += CT)
            rank[e] = atomicAdd(&cnt[dst[e]], 1);
    }
}

// ---------------- scan: per-block sums of PADDED counts ((cnt+3)&~3), dinv folded in ----------------
__global__ void scan_partial(const int* __restrict__ cnt, int* __restrict__ bsum,
                             float* __restrict__ dinv, int N) {
    __shared__ int wsum[4];
    const int t = threadIdx.x;
    const int base = blockIdx.x * 2048 + t * 8;
    int s = 0;
    #pragma unroll
    for (int i = 0; i < 8; ++i) {
        if (base + i < N) {
            const int c = cnt[base + i];
            dinv[base + i] = rsqrtf((float)(c + 1));   // +1 self loop
            s += (c + 3) & ~3;
        }
    }
    #pragma unroll
    for (int off = 32; off > 0; off >>= 1) s += __shfl_down(s, off);
    const int lane = t & 63, w = t >> 6;
    if (lane == 0) wsum[w] = s;
    __syncthreads();
    if (t == 0) bsum[blockIdx.x] = wsum[0] + wsum[1] + wsum[2] + wsum[3];
}

// scan_write: row_start (record units, multiples of 4) + {0,0.0f} pad records (<=3/node).
// Block offset computed in-kernel from raw bsum (S tiny) -> no separate scan launch.
__global__ void scan_write(const int* __restrict__ cnt, const int* __restrict__ bsum,
                           int* __restrict__ row_start, int2* __restrict__ pack, int N) {
    __shared__ int wsum[4];
    __shared__ int blockoff;
    const int t = threadIdx.x;
    if (t < 64) {
        int a = 0;
        for (int idx = t; idx < blockIdx.x; idx += 64) a += bsum[idx];
        #pragma unroll
        for (int off = 32; off > 0; off >>= 1) a += __shfl_down(a, off);
        if (t == 0) blockoff = a;
    }
    const int base = blockIdx.x * 2048 + t * 8;
    int c[8], v[8];
    #pragma unroll
    for (int i = 0; i < 8; ++i) {
        c[i] = (base + i < N) ? cnt[base + i] : 0;
        v[i] = (c[i] + 3) & ~3;
    }
    int s = v[0] + v[1] + v[2] + v[3] + v[4] + v[5] + v[6] + v[7];
    const int lane = t & 63, w = t >> 6;
    int incl = s;
    #pragma unroll
    for (int off = 1; off < 64; off <<= 1) {
        int u = __shfl_up(incl, off);
        if (lane >= off) incl += u;
    }
    if (lane == 63) wsum[w] = incl;
    __syncthreads();
    int woff = 0;
    for (int i = 0; i < w; ++i) woff += wsum[i];
    int run = blockoff + woff + (incl - s);
    const int2 zr = {0, 0};
    #pragma unroll
    for (int i = 0; i < 8; ++i) {
        if (base + i < N) {
            row_start[base + i] = run;
            for (int p = c[i]; p < v[i]; ++p) pack[run + p] = zr;   // pad: src=0, norm=0
            run += v[i];
        }
    }
}

// ---------------- fill packed CSR records {src, norm} (8B), no atomics, x4-vectorized ----------------
__global__ void fill_pack4(const int* __restrict__ src, const int* __restrict__ dst,
                           const int* __restrict__ rank, const int* __restrict__ row_start,
                           const float* __restrict__ dinv, int E, int2* __restrict__ pack) {
    const int q = blockIdx.x * blockDim.x + threadIdx.x;
    const int nq = E >> 2;
    if (q < nq) {
        const int4 s = ((const int4*)src)[q];
        const int4 d = ((const int4*)dst)[q];
        const int4 r = ((const int4*)rank)[q];
        int2 p;
        p.x = s.x; p.y = __float_as_int(dinv[s.x] * dinv[d.x]);
        pack[row_start[d.x] + r.x] = p;
        p.x = s.y; p.y = __float_as_int(dinv[s.y] * dinv[d.y]);
        pack[row_start[d.y] + r.y] = p;
        p.x = s.z; p.y = __float_as_int(dinv[s.z] * dinv[d.z]);
        pack[row_start[d.z] + r.z] = p;
        p.x = s.w; p.y = __float_as_int(dinv[s.w] * dinv[d.w]);
        pack[row_start[d.w] + r.w] = p;
    }
    if (q == 0) {   // tail (E not multiple of 4)
        for (int e = nq << 2; e < E; ++e) {
            int2 p;
            p.x = src[e]; p.y = __float_as_int(dinv[src[e]] * dinv[dst[e]]);
            pack[row_start[dst[e]] + rank[e]] = p;
        }
    }
}

// ---------------- GEMM2 (MFMA): h2[N,64](bf16) = agg_relu[N,128](bf16) @ W2[128,64] ----------------
// agg already has bias+relu applied -> b-frag is a raw 16B load.
__global__ __launch_bounds__(256) void gemm2_mfma(
        const ushort_t* __restrict__ agg,
        const float* __restrict__ W2, unsigned int* __restrict__ h2,
        int N, int NT, int NW) {
    const int tid  = threadIdx.x;
    const int lane = tid & 63;
    const int m    = lane & 15;
    const int quad = lane >> 4;
    const int gw   = blockIdx.x * 4 + (tid >> 6);

    bf16x8 a[4][4];                         // 4 col-tiles x 4 k-chunks
    #pragma unroll
    for (int ct = 0; ct < 4; ++ct)
        #pragma unroll
        for (int kc = 0; kc < 4; ++kc)
            #pragma unroll
            for (int j = 0; j < 8; ++j)
                a[ct][kc][j] = f2bf_s(W2[(size_t)(kc * 32 + quad * 8 + j) * OUT_DIM + ct * 16 + m]);

    for (int t = gw; t < NT; t += NW) {
        const int n0 = t * 16;
        int node = n0 + m; if (node >= N) node = N - 1;
        const ushort_t* ar = agg + (size_t)node * HID_DIM + quad * 8;
        f32x4 acc[4];
        #pragma unroll
        for (int ct = 0; ct < 4; ++ct) acc[ct] = (f32x4){0.f, 0.f, 0.f, 0.f};
        #pragma unroll
        for (int kc = 0; kc < 4; ++kc) {
            const bf16x8 b = *(const bf16x8*)(ar + kc * 32);
            #pragma unroll
            for (int ct = 0; ct < 4; ++ct)
                acc[ct] = __builtin_amdgcn_mfma_f32_16x16x32_bf16(a[ct][kc], b, acc[ct], 0, 0, 0);
        }
        if (n0 + m < N) {
            unsigned int* o = h2 + (size_t)(n0 + m) * (OUT_DIM / 2) + quad * 2;
            #pragma unroll
            for (int ct = 0; ct < 4; ++ct) {
                uint2 pv;
                pv.x = pack2(acc[ct][0], acc[ct][1]);
                pv.y = pack2(acc[ct][2], acc[ct][3]);
                *(uint2*)(o + ct * 8) = pv;
            }
        }
    }
}

// ---------------- gather aggregation over {src, norm} records ----------------
// pad records are {0, 0.0f} -> contribute nothing. bias pre-added (commutes), relu post-loop.
template<int D, bool BF16_OUT, bool RELU>
__global__ void gather_bf16(const ushort_t* __restrict__ h, const int2* __restrict__ pack,
                            const int* __restrict__ row_start, const int* __restrict__ cnt,
                            const float* __restrict__ dinv, const float* __restrict__ bias,
                            int N, void* __restrict__ outv) {
    const int TPN = D / 4;
    const int NPB = 256 / TPN;
    const int t = threadIdx.x;
    const int node = blockIdx.x * NPB + t / TPN;
    if (node >= N) return;
    const int f = (t & (TPN - 1)) * 4;
    const float dd = dinv[node];

    const ushort4_t self = *(const ushort4_t*)(h + (size_t)node * D + f);
    const float sn = dd * dd;
    float4 acc;
    acc.x = bf2f(self.x) * sn; acc.y = bf2f(self.y) * sn;
    acc.z = bf2f(self.z) * sn; acc.w = bf2f(self.w) * sn;
    const float4 bv = *(const float4*)(bias + f);
    acc.x += bv.x; acc.y += bv.y; acc.z += bv.z; acc.w += bv.w;

    const int2* pk = pack + row_start[node];       // 32B-aligned (start % 4 == 0)
    const int cpad = (cnt[node] + 3) & ~3;
    for (int e = 0; e < cpad; e += 4) {
        const int4 a = *(const int4*)(pk + e);
        const int4 b = *(const int4*)(pk + e + 2);
        {
            const ushort4_t v = *(const ushort4_t*)(h + (size_t)a.x * D + f);
            const float n = __int_as_float(a.y);
            acc.x += bf2f(v.x) * n; acc.y += bf2f(v.y) * n;
            acc.z += bf2f(v.z) * n; acc.w += bf2f(v.w) * n;
        }
        {
            const ushort4_t v = *(const ushort4_t*)(h + (size_t)a.z * D + f);
            const float n = __int_as_float(a.w);
            acc.x += bf2f(v.x) * n; acc.y += bf2f(v.y) * n;
            acc.z += bf2f(v.z) * n; acc.w += bf2f(v.w) * n;
        }
        {
            const ushort4_t v = *(const ushort4_t*)(h + (size_t)b.x * D + f);
            const float n = __int_as_float(b.y);
            acc.x += bf2f(v.x) * n; acc.y += bf2f(v.y) * n;
            acc.z += bf2f(v.z) * n; acc.w += bf2f(v.w) * n;
        }
        {
            const ushort4_t v = *(const ushort4_t*)(h + (size_t)b.z * D + f);
            const float n = __int_as_float(b.w);
            acc.x += bf2f(v.x) * n; acc.y += bf2f(v.y) * n;
            acc.z += bf2f(v.z) * n; acc.w += bf2f(v.w) * n;
        }
    }
    if (RELU) {
        acc.x = fmaxf(acc.x, 0.f); acc.y = fmaxf(acc.y, 0.f);
        acc.z = fmaxf(acc.z, 0.f); acc.w = fmaxf(acc.w, 0.f);
    }
    if (BF16_OUT) {
        unsigned int* out = (unsigned int*)outv;
        uint2 pv;
        pv.x = pack2(acc.x, acc.y);
        pv.y = pack2(acc.z, acc.w);
        *(uint2*)(out + ((size_t)node * D + f) / 2) = pv;
    } else {
        float* out = (float*)outv;
        *(float4*)(out + (size_t)node * D + f) = acc;
    }
}

extern "C" void kernel_launch(void* const* d_in, const int* in_sizes, int n_in,
                              void* d_out, int out_size, void* d_ws, size_t ws_size,
                              hipStream_t stream) {
    const float* x   = (const float*)d_in[0];
    const int*   ei  = (const int*)  d_in[1];
    const float* W1  = (const float*)d_in[2];
    const float* b1  = (const float*)d_in[3];
    const float* W2  = (const float*)d_in[4];
    const float* b2  = (const float*)d_in[5];
    float* out = (float*)d_out;

    const int N = in_sizes[0] / IN_DIM;     // 100000
    const int E = in_sizes[1] / 2;          // 1600000
    const int* src = ei;                    // edge_index[0]
    const int* dst = ei + E;                // edge_index[1]

    // workspace layout (4B units):
    // dinv[N] | cnt[N] | row_start[N] | bsum[1024] | align | pack[E+4N] int2
    // | h1[N*64] u32 (bf16 h1, reused as h2) | agg1[N*64] u32 (bf16; rank aliases it)
    const int PACK_CAP = E + 4 * N;
    float* dinv      = (float*)d_ws;
    int*   cnt       = (int*)(dinv + N);
    int*   row_start = cnt + N;
    int*   bsum      = row_start + N;
    size_t off       = (size_t)(3 * N + 1024);
    off = (off + 3) & ~(size_t)3;           // 16B-align pack
    int2*  pack      = (int2*)((int*)d_ws + off);
    unsigned int* h1 = (unsigned int*)(pack + PACK_CAP);
    unsigned int* agg1 = h1 + (size_t)N * (HID_DIM / 2);
    int*   rank      = (int*)agg1;          // alive only until fill_pack (E <= N*64)
    unsigned int* h2 = h1;                  // reuse after gather128

    const int B = 256;
    const int S = (N + 2047) / 2048;        // scan blocks
    const int NT = (N + 15) / 16;           // 16-node MFMA tiles

    // 1) CSR counts + rank, fused with GEMM1 (independent work hides atomic throughput floor)
    hipMemsetAsync(cnt, 0, (size_t)N * sizeof(int), stream);
    fused_gemm1_count<<<512, 256, 0, stream>>>(x, W1, h1, dst, cnt, rank, N, E, NT);

    // 2) scan (dinv folded into scan_partial; scan_write self-computes block offsets + pads)
    scan_partial<<<S, 256, 0, stream>>>(cnt, bsum, dinv, N);
    scan_write<<<S, 256, 0, stream>>>(cnt, bsum, row_start, pack, N);

    // 3) fill packed CSR records {src, norm}
    fill_pack4<<<((E >> 2) + B - 1) / B, B, 0, stream>>>(src, dst, rank, row_start, dinv, E, pack);

    // 4) agg1 = relu(gather(h1) + b1)  (bf16 out; overwrites rank)
    gather_bf16<HID_DIM, true, true><<<(N + 7) / 8, 256, 0, stream>>>(
        (const ushort_t*)h1, pack, row_start, cnt, dinv, b1, N, (void*)agg1);

    // 5) h2 = agg1 @ W2  (bf16 out, MFMA, raw b-frag loads)
    gemm2_mfma<<<768, 256, 0, stream>>>(
        (const ushort_t*)agg1, W2, h2, N, NT, 768 * 4);

    // 6) out = b2 + gather(h2)  (f32 out)
    gather_bf16<OUT_DIM, false, false><<<(N + 15) / 16, 256, 0, stream>>>(
        (const ushort_t*)h2, pack, row_start, cnt, dinv, b2, N, (void*)out);
}